// Round 1
// baseline (117.793 us; speedup 1.0000x reference)
//
#include <hip/hip_runtime.h>

// Problem constants (from reference)
#define BB   8
#define CC   256
#define HWN  16384        // 128*128
#define PP   30
#define KD   128
#define GG   5            // prototypes per class
// d_out float offsets
#define OFF_Q   (33554432u)             // 8*256*128*128
#define OFF_SIM (OFF_Q + 30720u)        // + 30*8*128

// ---------------- kernel 1: q[p,b,k] = Wq[p/G] @ proto[p,b,:] + bq[p/G] --------
__global__ void qproj_kernel(const float* __restrict__ proto,  // [P,B,C]
                             const float* __restrict__ Wq,     // [6,128,C]
                             const float* __restrict__ bq,     // [6,128]
                             float* __restrict__ qout)         // [P,B,128]
{
    int pb = blockIdx.x;           // p*B + b
    int p = pb / BB;
    int g = p / GG;
    int k = threadIdx.x;           // 0..127
    __shared__ float ps[CC];
    for (int c = threadIdx.x; c < CC; c += 128) ps[c] = proto[pb * CC + c];
    __syncthreads();
    const float* wrow = Wq + (g * KD + k) * CC;
    float acc = 0.f;
    #pragma unroll 4
    for (int c = 0; c < CC; ++c) acc += ps[c] * wrow[c];
    qout[pb * KD + k] = acc + bq[g * KD + k];
}

// ---------------- kernel 2: A[b,p,c] = sum_k q[p,b,k]*Wk[k,c]; c0[b,p]=q.bk ----
__global__ void aproj_kernel(const float* __restrict__ qin,   // [P,B,128]
                             const float* __restrict__ Wk,    // [128,C]
                             const float* __restrict__ bk,    // [128]
                             float* __restrict__ A,           // [B,P,C] (ws)
                             float* __restrict__ c0)          // [B,P]   (ws)
{
    int pb = blockIdx.x;           // p*B + b
    int p = pb / BB, b = pb % BB;
    int c = threadIdx.x;           // 0..255
    __shared__ float qs[KD];
    if (threadIdx.x < KD) qs[threadIdx.x] = qin[pb * KD + threadIdx.x];
    __syncthreads();
    float acc = 0.f;
    #pragma unroll 4
    for (int k = 0; k < KD; ++k) acc += qs[k] * Wk[k * CC + c];
    A[(b * PP + p) * CC + c] = acc;
    if (threadIdx.x == 0) {
        float s = 0.f;
        for (int k = 0; k < KD; ++k) s += qs[k] * bk[k];
        c0[b * PP + p] = s;
    }
}

// ---------------- kernel 3: fused sim + softmax-max + weighted output ----------
__global__ __launch_bounds__(256) void fused_kernel(
    const float* __restrict__ X,    // [B,C,HW]
    const float* __restrict__ A,    // [B,P,C]
    const float* __restrict__ c0,   // [B,P]
    float* __restrict__ out0,       // [B,C,HW]
    float* __restrict__ sim)        // [B,P,HW]
{
    const int b = blockIdx.y;
    const int n = blockIdx.x * 256 + threadIdx.x;

    __shared__ float4 As[PP][CC / 4];     // 30 KB
    __shared__ float  c0s[PP];
    {
        const float4* A4 = (const float4*)(A + (size_t)b * PP * CC);
        float4* dst = (float4*)As;
        for (int i = threadIdx.x; i < PP * CC / 4; i += 256) dst[i] = A4[i];
        if (threadIdx.x < PP) c0s[threadIdx.x] = c0[b * PP + threadIdx.x];
    }
    __syncthreads();

    float acc[PP];
    #pragma unroll
    for (int p = 0; p < PP; ++p) acc[p] = 0.f;

    const float* xb = X + (size_t)b * CC * HWN + n;

    for (int c4 = 0; c4 < CC / 4; ++c4) {
        float x0 = xb[(4 * c4 + 0) * HWN];
        float x1 = xb[(4 * c4 + 1) * HWN];
        float x2 = xb[(4 * c4 + 2) * HWN];
        float x3 = xb[(4 * c4 + 3) * HWN];
        #pragma unroll
        for (int p = 0; p < PP; ++p) {
            float4 a = As[p][c4];
            acc[p] += a.x * x0 + a.y * x1 + a.z * x2 + a.w * x3;
        }
    }

    // sim = acc + c0 ; write sim out
    float m = -1e30f;
    #pragma unroll
    for (int p = 0; p < PP; ++p) {
        acc[p] += c0s[p];
        sim[((size_t)b * PP + p) * HWN + n] = acc[p];
        m = fmaxf(m, acc[p] * (1.f / 6.f));
    }
    float s = 0.f;
    #pragma unroll
    for (int p = 0; p < PP; ++p) s += __expf(acc[p] * (1.f / 6.f) - m);
    const float w = 1.f / s;   // max_p softmax == 1/sum(exp(l - lmax))

    // weighted output pass (X re-read; tile should be L2-hot)
    float* ob = out0 + (size_t)b * CC * HWN + n;
    for (int c = 0; c < CC; ++c) ob[c * HWN] = xb[c * HWN] * w;
}

extern "C" void kernel_launch(void* const* d_in, const int* in_sizes, int n_in,
                              void* d_out, int out_size, void* d_ws, size_t ws_size,
                              hipStream_t stream) {
    const float* X     = (const float*)d_in[0];   // [8,256,128,128]
    const float* proto = (const float*)d_in[1];   // [30,8,256]
    const float* Wk    = (const float*)d_in[2];   // [128,256]
    const float* bk    = (const float*)d_in[3];   // [128]
    const float* Wq    = (const float*)d_in[4];   // [6,128,256]
    const float* bq    = (const float*)d_in[5];   // [6,128]

    float* out  = (float*)d_out;
    float* qout = out + OFF_Q;
    float* sim  = out + OFF_SIM;

    float* A  = (float*)d_ws;                 // 61440 floats
    float* c0 = A + BB * PP * CC;             // 240 floats

    qproj_kernel<<<PP * BB, 128, 0, stream>>>(proto, Wq, bq, qout);
    aproj_kernel<<<PP * BB, 256, 0, stream>>>(qout, Wk, bk, A, c0);

    dim3 grid(HWN / 256, BB);
    fused_kernel<<<grid, 256, 0, stream>>>(X, A, c0, out, sim);
}

// Round 2
// 100.179 us; speedup vs baseline: 1.1758x; 1.1758x over previous
//
#include <hip/hip_runtime.h>

#define BB   8
#define CC   256
#define HWN  16384        // 128*128
#define PP   30
#define KD   128
#define GG   5
// d_out float offsets
#define OFF_Q   (33554432u)             // 8*256*128*128
#define OFF_SIM (OFF_Q + 30720u)        // + 30*8*128

// ---- kernel 1: fused q-projection + A/c0 build (tiny; 240 blocks) ----------
// q[p,b,k] = Wq[p/G,k,:] . proto[p,b,:] + bq[p/G,k]
// A[b,p,c] = sum_k q[p,b,k]*Wk[k,c] ;  c0[b,p] = sum_k q[p,b,k]*bk[k]
__global__ __launch_bounds__(256) void proj_kernel(
    const float* __restrict__ proto,  // [P,B,C]
    const float* __restrict__ Wq,     // [6,128,C]
    const float* __restrict__ bq,     // [6,128]
    const float* __restrict__ Wk,     // [128,C]
    const float* __restrict__ bk,     // [128]
    float* __restrict__ qout,         // [P,B,128] (into d_out)
    float* __restrict__ A,            // [B,P,C]   (ws)
    float* __restrict__ c0)           // [B,P]     (ws)
{
    const int pb = blockIdx.x;        // p*B + b
    const int p = pb / BB, b = pb % BB, g = p / GG;
    const int tid = threadIdx.x;

    __shared__ float ps[CC];
    __shared__ float qs[KD];

    for (int c = tid; c < CC; c += 256) ps[c] = proto[pb * CC + c];
    __syncthreads();

    if (tid < KD) {
        const float* wrow = Wq + (size_t)(g * KD + tid) * CC;
        float a = 0.f;
        #pragma unroll 4
        for (int c = 0; c < CC; ++c) a += ps[c] * wrow[c];
        a += bq[g * KD + tid];
        qout[pb * KD + tid] = a;
        qs[tid] = a;
    }
    __syncthreads();

    float a = 0.f;
    #pragma unroll 4
    for (int k = 0; k < KD; ++k) a += qs[k] * Wk[k * CC + tid];
    A[(size_t)(b * PP + p) * CC + tid] = a;

    if (tid == 0) {
        float s = 0.f;
        for (int k = 0; k < KD; ++k) s += qs[k] * bk[k];
        c0[b * PP + p] = s;
    }
}

// ---- kernel 2: fused sim + softmax-max + weighted output -------------------
// Block: 64 positions x 4 waves; wave q handles channel quarter q.
__global__ __launch_bounds__(256) void fused_kernel(
    const float* __restrict__ X,    // [B,C,HW]
    const float* __restrict__ A,    // [B,P,C]
    const float* __restrict__ c0,   // [B,P]
    float* __restrict__ out0,       // [B,C,HW]
    float* __restrict__ sim)        // [B,P,HW]
{
    const int b    = blockIdx.y;
    const int tile = blockIdx.x;          // 0..255
    const int tid  = threadIdx.x;
    const int pos  = tid & 63;
    const int q    = tid >> 6;            // wave id == channel quarter
    const int n    = tile * 64 + pos;

    __shared__ float4 As4[PP][CC / 4];    // 30720 B; reused as reduce buffer
    __shared__ float  c0s[PP];
    __shared__ float  wbuf[64];

    {
        const float4* A4 = (const float4*)(A + (size_t)b * PP * CC);
        float4* dst = (float4*)As4;
        for (int i = tid; i < PP * CC / 4; i += 256) dst[i] = A4[i];
        if (tid < PP) c0s[tid] = c0[b * PP + tid];
    }
    __syncthreads();

    float acc[PP];
    #pragma unroll
    for (int p = 0; p < PP; ++p) acc[p] = 0.f;

    const float* xb = X + (size_t)b * CC * HWN + n;
    const int c4base = q * 16;            // 16 float4-channel-groups per wave

    #pragma unroll 4
    for (int i = 0; i < 16; ++i) {
        const int c4 = c4base + i;
        const float x0 = xb[(4 * c4 + 0) * HWN];
        const float x1 = xb[(4 * c4 + 1) * HWN];
        const float x2 = xb[(4 * c4 + 2) * HWN];
        const float x3 = xb[(4 * c4 + 3) * HWN];
        #pragma unroll
        for (int p = 0; p < PP; ++p) {
            const float4 a = As4[p][c4];   // wave-uniform -> LDS broadcast
            acc[p] += a.x * x0 + a.y * x1 + a.z * x2 + a.w * x3;
        }
    }
    __syncthreads();                       // done reading As4

    float* red = (float*)As4;              // [3][64][PP] = 23040 B, fits
    if (q) {
        float* r = red + ((q - 1) * 64 + pos) * PP;
        #pragma unroll
        for (int p = 0; p < PP; ++p) r[p] = acc[p];
    }
    __syncthreads();

    if (q == 0) {
        #pragma unroll
        for (int j = 0; j < 3; ++j) {
            const float* r = red + (j * 64 + pos) * PP;
            #pragma unroll
            for (int p = 0; p < PP; ++p) acc[p] += r[p];
        }
        float m = -1e30f;
        #pragma unroll
        for (int p = 0; p < PP; ++p) {
            acc[p] += c0s[p];
            sim[((size_t)b * PP + p) * HWN + n] = acc[p];
            m = fmaxf(m, acc[p] * (1.f / 6.f));
        }
        float s = 0.f;
        #pragma unroll
        for (int p = 0; p < PP; ++p) s += __expf(acc[p] * (1.f / 6.f) - m);
        wbuf[pos] = 1.f / s;               // max_p softmax == 1/sum exp(l-lmax)
    }
    __syncthreads();

    const float w = wbuf[pos];
    float* ob = out0 + (size_t)b * CC * HWN + n;
    const int cbase = q * 64;
    #pragma unroll 4
    for (int c = cbase; c < cbase + 64; ++c)
        ob[c * HWN] = xb[c * HWN] * w;     // X re-read is L2-hot
}

extern "C" void kernel_launch(void* const* d_in, const int* in_sizes, int n_in,
                              void* d_out, int out_size, void* d_ws, size_t ws_size,
                              hipStream_t stream) {
    const float* X     = (const float*)d_in[0];
    const float* proto = (const float*)d_in[1];
    const float* Wk    = (const float*)d_in[2];
    const float* bk    = (const float*)d_in[3];
    const float* Wq    = (const float*)d_in[4];
    const float* bq    = (const float*)d_in[5];

    float* out  = (float*)d_out;
    float* qout = out + OFF_Q;
    float* sim  = out + OFF_SIM;

    float* A  = (float*)d_ws;              // 61440 floats
    float* c0 = A + BB * PP * CC;          // 240 floats

    proj_kernel<<<PP * BB, 256, 0, stream>>>(proto, Wq, bq, Wk, bk, qout, A, c0);

    dim3 grid(HWN / 64, BB);
    fused_kernel<<<grid, 256, 0, stream>>>(X, A, c0, out, sim);
}

// Round 4
// 97.728 us; speedup vs baseline: 1.2053x; 1.0251x over previous
//
#include <hip/hip_runtime.h>

#define BB   8
#define CC   256
#define HWN  16384        // 128*128
#define PP   30
#define KD   128
#define GG   5
// d_out float offsets
#define OFF_Q   (33554432u)             // 8*256*128*128
#define OFF_SIM (OFF_Q + 30720u)        // + 30*8*128

typedef float f32x4 __attribute__((ext_vector_type(4)));

// ---- kernel 1: fused q-projection + A/c0 build (tiny; 240 blocks) ----------
__global__ __launch_bounds__(256) void proj_kernel(
    const float* __restrict__ proto,  // [P,B,C]
    const float* __restrict__ Wq,     // [6,128,C]
    const float* __restrict__ bq,     // [6,128]
    const float* __restrict__ Wk,     // [128,C]
    const float* __restrict__ bk,     // [128]
    float* __restrict__ qout,         // [P,B,128] (into d_out)
    float* __restrict__ A,            // [B,P,C]   (ws)
    float* __restrict__ c0)           // [B,P]     (ws)
{
    const int pb = blockIdx.x;        // p*B + b
    const int p = pb / BB, b = pb % BB, g = p / GG;
    const int tid = threadIdx.x;

    __shared__ float ps[CC];
    __shared__ float qs[KD];

    for (int c = tid; c < CC; c += 256) ps[c] = proto[pb * CC + c];
    __syncthreads();

    if (tid < KD) {
        const float* wrow = Wq + (size_t)(g * KD + tid) * CC;
        float a = 0.f;
        #pragma unroll 4
        for (int c = 0; c < CC; ++c) a += ps[c] * wrow[c];
        a += bq[g * KD + tid];
        qout[pb * KD + tid] = a;
        qs[tid] = a;
    }
    __syncthreads();

    float a = 0.f;
    #pragma unroll 4
    for (int k = 0; k < KD; ++k) a += qs[k] * Wk[k * CC + tid];
    A[(size_t)(b * PP + p) * CC + tid] = a;

    if (tid == 0) {
        float s = 0.f;
        for (int k = 0; k < KD; ++k) s += qs[k] * bk[k];
        c0[b * PP + p] = s;
    }
}

// ---- kernel 2: fused sim + softmax-max + weighted output -------------------
// Block: 256 positions, 4 waves; wave q owns channel quarter q; each thread
// owns 4 consecutive positions (float4 loads/stores, 16B/lane).
// A values live in VGPRs (lane l holds channel q*64+l), broadcast by readlane.
__global__ __launch_bounds__(256) void fused_kernel(
    const float* __restrict__ X,    // [B,C,HW]
    const float* __restrict__ A,    // [B,P,C]
    const float* __restrict__ c0,   // [B,P]
    float* __restrict__ out0,       // [B,C,HW]
    float* __restrict__ sim)        // [B,P,HW]
{
    const int b    = blockIdx.y;
    const int tid  = threadIdx.x;
    const int lane = tid & 63;
    const int q    = tid >> 6;
    const int n0   = blockIdx.x * 256 + lane * 4;

    __shared__ float red[3][64][31];   // padded: stride 31 -> conflict-free
    __shared__ float wbuf[64][4];
    __shared__ float c0s[PP];

    if (tid < PP) c0s[tid] = c0[b * PP + tid];

    // A quarter into registers: lane l holds A[b][p][q*64+l]
    float a[PP];
    #pragma unroll
    for (int p = 0; p < PP; ++p)
        a[p] = A[(size_t)(b * PP + p) * CC + q * 64 + lane];

    float acc[PP][4];
    #pragma unroll
    for (int p = 0; p < PP; ++p) {
        acc[p][0] = 0.f; acc[p][1] = 0.f; acc[p][2] = 0.f; acc[p][3] = 0.f;
    }

    const float* xb = X + (size_t)b * CC * HWN + n0;

    for (int i = 0; i < 64; i += 4) {          // 16 batches of 4 channels
        f32x4 xv[4];
        #pragma unroll
        for (int u = 0; u < 4; ++u)
            xv[u] = *(const f32x4*)(xb + (size_t)(q * 64 + i + u) * HWN);
        #pragma unroll
        for (int u = 0; u < 4; ++u) {
            const int ch = i + u;              // uniform -> SGPR lane index
            #pragma unroll
            for (int p = 0; p < PP; ++p) {
                const float av = __int_as_float(
                    __builtin_amdgcn_readlane(__float_as_int(a[p]), ch));
                acc[p][0] += av * xv[u].x;
                acc[p][1] += av * xv[u].y;
                acc[p][2] += av * xv[u].z;
                acc[p][3] += av * xv[u].w;
            }
        }
    }
    __syncthreads();

    // cross-wave reduction, chunked by position j (static indices only)
    #pragma unroll
    for (int j = 0; j < 4; ++j) {
        if (q) {
            #pragma unroll
            for (int p = 0; p < PP; ++p) red[q - 1][lane][p] = acc[p][j];
        }
        __syncthreads();
        if (q == 0) {
            #pragma unroll
            for (int k = 0; k < 3; ++k)
                #pragma unroll
                for (int p = 0; p < PP; ++p) acc[p][j] += red[k][lane][p];
        }
        __syncthreads();
    }

    if (q == 0) {
        #pragma unroll
        for (int p = 0; p < PP; ++p) {
            const float cc = c0s[p];
            acc[p][0] += cc; acc[p][1] += cc; acc[p][2] += cc; acc[p][3] += cc;
            f32x4 sv;
            sv.x = acc[p][0]; sv.y = acc[p][1]; sv.z = acc[p][2]; sv.w = acc[p][3];
            __builtin_nontemporal_store(sv,
                (f32x4*)(sim + ((size_t)b * PP + p) * HWN + n0));
        }
        #pragma unroll
        for (int j = 0; j < 4; ++j) {
            float m = -1e30f;
            #pragma unroll
            for (int p = 0; p < PP; ++p) m = fmaxf(m, acc[p][j]);
            float s = 0.f;
            #pragma unroll
            for (int p = 0; p < PP; ++p) s += __expf((acc[p][j] - m) * (1.f / 6.f));
            wbuf[lane][j] = 1.f / s;           // max_p softmax == 1/sum exp
        }
    }
    __syncthreads();

    f32x4 wv = *(const f32x4*)(&wbuf[lane][0]);
    float* ob = out0 + (size_t)b * CC * HWN + n0;
    #pragma unroll 4
    for (int i = 0; i < 64; ++i) {
        const size_t off = (size_t)(q * 64 + i) * HWN;
        f32x4 x = __builtin_nontemporal_load((const f32x4*)(xb + off));
        f32x4 o = x * wv;
        __builtin_nontemporal_store(o, (f32x4*)(ob + off));
    }
}

extern "C" void kernel_launch(void* const* d_in, const int* in_sizes, int n_in,
                              void* d_out, int out_size, void* d_ws, size_t ws_size,
                              hipStream_t stream) {
    const float* X     = (const float*)d_in[0];
    const float* proto = (const float*)d_in[1];
    const float* Wk    = (const float*)d_in[2];
    const float* bk    = (const float*)d_in[3];
    const float* Wq    = (const float*)d_in[4];
    const float* bq    = (const float*)d_in[5];

    float* out  = (float*)d_out;
    float* qout = out + OFF_Q;
    float* sim  = out + OFF_SIM;

    float* A  = (float*)d_ws;              // 61440 floats
    float* c0 = A + BB * PP * CC;          // 240 floats

    proj_kernel<<<PP * BB, 256, 0, stream>>>(proto, Wq, bq, Wk, bk, qout, A, c0);

    dim3 grid(HWN / 256, BB);              // 64 x 8 = 512 blocks
    fused_kernel<<<grid, 256, 0, stream>>>(X, A, c0, out, sim);
}